// Round 4
// baseline (255.541 us; speedup 1.0000x reference)
//
#include <hip/hip_runtime.h>
#include <hip/hip_cooperative_groups.h>
#include <cstdint>
#include <cstddef>

namespace cg = cooperative_groups;

#define MROWS 1024
#define NCOLS 4096
#define TOPK 16
#define NKEYS (MROWS * TOPK)   // 16384
#define SCHUNK 2048            // per-block local-sort span (16 KiB LDS)
#define SBLOCKS (NKEYS / SCHUNK)  // 8

typedef unsigned long long u64;

// key = (p_bits << 22) | ((1023-row) << 12) | (4095-col)
// u64 descending == p desc, then row asc, then col asc (flat-index tie-break).
__device__ inline int key_col(u64 k) { return (NCOLS - 1) - (int)(k & 0xFFFull); }
__device__ inline int key_row(u64 k) { return (MROWS - 1) - (int)((k >> 12) & 0x3FFull); }

// single-wave LDS ordering fence: wait LDS only, do NOT drain vmcnt
#define WAVE_FENCE() __asm__ volatile("s_waitcnt lgkmcnt(0)" ::: "memory")

// ---------------- wave (64-lane) reduce helpers ----------------
__device__ inline float wave_max_f(float v) {
    #pragma unroll
    for (int off = 32; off >= 1; off >>= 1)
        v = fmaxf(v, __shfl_xor(v, off, 64));
    return v;
}
__device__ inline float wave_sum_f(float v) {
    #pragma unroll
    for (int off = 32; off >= 1; off >>= 1)
        v += __shfl_xor(v, off, 64);
    return v;
}
__device__ inline u64 wave_max_u64(u64 v) {
    #pragma unroll
    for (int off = 32; off >= 1; off >>= 1) {
        u64 o = __shfl_xor(v, off, 64);
        v = o > v ? o : v;
    }
    return v;
}

// ---------------- K1: per-block partial max over scores ----------------
__global__ __launch_bounds__(256) void k_partial_max(const float* __restrict__ s,
                                                     float* __restrict__ pmax) {
    int b = blockIdx.x, t = threadIdx.x;
    const float4* s4 = (const float4*)s;
    float m = -3.4e38f;
    int base = b * 4096 + t;
    #pragma unroll
    for (int i = 0; i < 16; ++i) {
        float4 v = s4[base + i * 256];
        m = fmaxf(m, fmaxf(fmaxf(v.x, v.y), fmaxf(v.z, v.w)));
    }
    m = wave_max_f(m);
    __shared__ float sm[4];
    if ((t & 63) == 0) sm[t >> 6] = m;
    __syncthreads();
    if (t == 0) pmax[b] = fmaxf(fmaxf(sm[0], sm[1]), fmaxf(sm[2], sm[3]));
}

// ---------------- K2: inline gmax + partial sum of exp; block0 builds bitmap ----
__global__ __launch_bounds__(256) void k_partial_sum2(const float* __restrict__ s,
                                                      const float* __restrict__ pmax,
                                                      float* __restrict__ psum,
                                                      unsigned* __restrict__ bitmap,
                                                      const int* __restrict__ cont,
                                                      const int* __restrict__ prev) {
    int b = blockIdx.x, t = threadIdx.x;
    __shared__ float fred[4];
    if (b == 0 && t < 128) bitmap[t] = 0u;
    float m = pmax[t];
    m = wave_max_f(m);
    if ((t & 63) == 0) fred[t >> 6] = m;
    __syncthreads();
    float gmax = fmaxf(fmaxf(fred[0], fred[1]), fmaxf(fred[2], fred[3]));

    const float4* s4 = (const float4*)s;
    float acc = 0.0f;
    int base = b * 4096 + t;
    #pragma unroll
    for (int i = 0; i < 16; ++i) {
        float4 v = s4[base + i * 256];
        acc += expf(v.x - gmax) + expf(v.y - gmax) + expf(v.z - gmax) + expf(v.w - gmax);
    }
    acc = wave_sum_f(acc);
    __syncthreads();
    if ((t & 63) == 0) fred[t >> 6] = acc;
    __syncthreads();
    if (t == 0) psum[b] = fred[0] + fred[1] + fred[2] + fred[3];
    if (b == 0) {
        for (int i = t; i < MROWS; i += 256) {
            if (cont[i]) {
                int c = prev[i];
                atomicOr(&bitmap[c >> 5], 1u << (c & 31));
            }
        }
    }
}

// ---------------- K3: policy write (float4) + per-row masked top-16 keys -------
__global__ __launch_bounds__(256) void k_policy_top16(const float* __restrict__ s,
                                                      const float* __restrict__ pmax,
                                                      const float* __restrict__ psum,
                                                      const unsigned* __restrict__ bitmap,
                                                      const int* __restrict__ cont,
                                                      float* __restrict__ policy,
                                                      u64* __restrict__ outkeys) {
    __shared__ u64 keys[NCOLS];   // 32 KiB
    __shared__ u64 red[4];
    __shared__ float fred[4];
    int r = blockIdx.x, t = threadIdx.x;
    float m = pmax[t];
    m = wave_max_f(m);
    if ((t & 63) == 0) fred[t >> 6] = m;
    __syncthreads();
    float gmax = fmaxf(fmaxf(fred[0], fred[1]), fmaxf(fred[2], fred[3]));
    float sv = psum[t];
    sv = wave_sum_f(sv);
    __syncthreads();
    if ((t & 63) == 0) fred[t >> 6] = sv;
    __syncthreads();
    float gsum = fred[0] + fred[1] + fred[2] + fred[3];
    float inv = 1.0f / gsum;

    int cg_ = cont[r];
    const float4* s4 = (const float4*)(s + (size_t)r * NCOLS);
    float4* p4 = (float4*)(policy + (size_t)r * NCOLS);
    u64 rowpart = (u64)(MROWS - 1 - r) << 12;
    #pragma unroll
    for (int i = 0; i < 4; ++i) {
        int f = t + i * 256;          // float4 index, 1024 per row
        float4 v = s4[f];
        float4 pv;
        pv.x = expf(v.x - gmax) * inv;
        pv.y = expf(v.y - gmax) * inv;
        pv.z = expf(v.z - gmax) * inv;
        pv.w = expf(v.w - gmax) * inv;
        p4[f] = pv;
        int c0 = 4 * f;
        unsigned bmw = bitmap[c0 >> 5];
        float pe[4] = {pv.x, pv.y, pv.z, pv.w};
        #pragma unroll
        for (int e = 0; e < 4; ++e) {
            int c = c0 + e;
            u64 kk = 0ull;
            if (!cg_ && !((bmw >> (c & 31)) & 1u))
                kk = ((u64)__float_as_uint(pe[e]) << 22) | rowpart | (u64)(NCOLS - 1 - c);
            keys[c] = kk;
        }
    }
    __syncthreads();
    if (cg_) {
        if (t < TOPK) outkeys[r * TOPK + t] = 0ull;
        return;
    }
    for (int pass = 0; pass < TOPK; ++pass) {
        u64 best = 0ull;
        #pragma unroll
        for (int i = 0; i < 16; ++i) {
            u64 kk = keys[t + i * 256];
            best = kk > best ? kk : best;
        }
        best = wave_max_u64(best);
        if ((t & 63) == 0) red[t >> 6] = best;
        __syncthreads();
        if (t == 0) {
            u64 b0 = red[0] > red[1] ? red[0] : red[1];
            u64 b1 = red[2] > red[3] ? red[2] : red[3];
            u64 b = b0 > b1 ? b0 : b1;
            outkeys[r * TOPK + pass] = b;
            keys[key_col(b)] = 0ull;
        }
        __syncthreads();
    }
}

// ---------------- K4: cooperative fused bitonic sort + serial scan -------------
__global__ __launch_bounds__(1024) void k_sortscan(u64* __restrict__ keys,
                                                   const int* __restrict__ cont,
                                                   const int* __restrict__ prev,
                                                   float* __restrict__ actions,
                                                   const unsigned* __restrict__ bitmap,
                                                   const float* __restrict__ policy) {
    cg::grid_group grid = cg::this_grid();
    __shared__ u64 sk[SCHUNK];   // 16 KiB; re-used by the scan phase
    int t = threadIdx.x, b = blockIdx.x;
    int off = b * SCHUNK;
    int gid = b * 1024 + t;

    // ---- local full bitonic sort of this 2048-key chunk ----
    sk[t] = keys[off + t];
    sk[t + 1024] = keys[off + t + 1024];
    __syncthreads();
    for (int k = 2; k <= SCHUNK; k <<= 1) {
        for (int j = k >> 1; j >= 1; j >>= 1) {
            int i = ((t & ~(j - 1)) << 1) | (t & (j - 1));
            int p = i | j;
            bool desc = (((off + i) & k) == 0);
            u64 a = sk[i], bb = sk[p];
            bool sw = desc ? (a < bb) : (a > bb);
            if (sw) { sk[i] = bb; sk[p] = a; }
            __syncthreads();
        }
    }
    keys[off + t] = sk[t];
    keys[off + t + 1024] = sk[t + 1024];
    grid.sync();

    // ---- merge stages k = 4096, 8192, 16384 ----
    for (int k = 4096; k <= 16384; k <<= 1) {
        for (int j = k >> 1; j >= SCHUNK; j >>= 1) {
            int i = ((gid & ~(j - 1)) << 1) | (gid & (j - 1));
            int p = i | j;
            bool desc = ((i & k) == 0);
            u64 a = keys[i], bb = keys[p];
            bool sw = desc ? (a < bb) : (a > bb);
            if (sw) { keys[i] = bb; keys[p] = a; }
            grid.sync();
        }
        // local finish j <= 1024 (within-chunk; direction uniform per chunk)
        sk[t] = keys[off + t];
        sk[t + 1024] = keys[off + t + 1024];
        __syncthreads();
        bool desc = ((off & k) == 0);
        for (int j = SCHUNK >> 1; j >= 1; j >>= 1) {
            int i = ((t & ~(j - 1)) << 1) | (t & (j - 1));
            int p = i | j;
            u64 a = sk[i], bb = sk[p];
            bool sw = desc ? (a < bb) : (a > bb);
            if (sw) { sk[i] = bb; sk[p] = a; }
            __syncthreads();
        }
        keys[off + t] = sk[t];
        keys[off + t + 1024] = sk[t + 1024];
        grid.sync();
    }

    // ---- serial greedy scan: block 0, wave 0 only (no __syncthreads below) ----
    if (b != 0 || t >= 64) return;
    int lane = t;
    unsigned* rowdone = (unsigned*)sk;            // 32 u32
    unsigned* coldone = rowdone + 32;             // 128 u32
    float* act = (float*)(coldone + 128);         // 1024 f32

    if (lane < 32) rowdone[lane] = 0u;
    coldone[lane] = bitmap[lane];
    coldone[lane + 64] = bitmap[lane + 64];
    WAVE_FENCE();
    int K = 0;
    #pragma unroll
    for (int j = 0; j < 16; ++j) {
        int i = j * 64 + lane;
        int cgf = cont[i];
        act[i] = cgf ? (float)prev[i] : -1.0f;
        if (cgf) atomicOr(&rowdone[i >> 5], 1u << (i & 31));
        K += (cgf == 0);
    }
    #pragma unroll
    for (int off2 = 32; off2 >= 1; off2 >>= 1) K += __shfl_xor(K, off2, 64);
    WAVE_FENCE();

    int assigned = 0;
    u64 key = keys[lane];
    u64 kp1 = keys[64 + lane];
    for (int base = 0; base < NKEYS && assigned < K; base += 64) {
        u64 kp2 = (base + 128 < NKEYS) ? keys[base + 128 + lane] : 0ull;
        bool valid = key != 0ull;
        if (__ballot(valid) == 0ull) break;
        int row = key_row(key);
        int col = key_col(key);
        unsigned rw = rowdone[row >> 5];
        unsigned cw = coldone[col >> 5];
        bool rfree = valid && !((rw >> (row & 31)) & 1u);
        bool cfree = valid && !((cw >> (col & 31)) & 1u);
        u64 alive = __ballot(rfree && cfree);
        u64 comm = 0ull;
        while (alive) {
            int j = __ffsll((long long)alive) - 1;
            int rj = __shfl(row, j, 64);
            int cj = __shfl(col, j, 64);
            u64 conf = __ballot(row == rj || col == cj);  // includes j itself
            comm |= 1ull << j;
            alive &= ~conf;
        }
        if ((comm >> lane) & 1ull) {
            atomicOr(&rowdone[row >> 5], 1u << (row & 31));
            atomicOr(&coldone[col >> 5], 1u << (col & 31));
            act[row] = (float)col;
        }
        assigned += __popcll(comm);
        key = kp1; kp1 = kp2;
        WAVE_FENCE();
    }

    // exact-greedy fallback for rows that exhausted their top-16 (P ~ 2e-12)
    for (int guard = 0; assigned < K && guard < 2048; ++guard) {
        u64 best = 0ull;
        for (int r = 0; r < MROWS; ++r) {
            if ((rowdone[r >> 5] >> (r & 31)) & 1u) continue;
            const float* prow = policy + (size_t)r * NCOLS;
            u64 rowpart = (u64)(MROWS - 1 - r) << 12;
            for (int c = lane; c < NCOLS; c += 64) {
                if ((coldone[c >> 5] >> (c & 31)) & 1u) continue;
                u64 kk = ((u64)__float_as_uint(prow[c]) << 22) | rowpart |
                         (u64)(NCOLS - 1 - c);
                best = kk > best ? kk : best;
            }
        }
        best = wave_max_u64(best);
        if (best == 0ull) break;
        if (lane == 0) {
            int row = key_row(best), col = key_col(best);
            rowdone[row >> 5] |= 1u << (row & 31);
            coldone[col >> 5] |= 1u << (col & 31);
            act[row] = (float)col;
        }
        ++assigned;
        WAVE_FENCE();
    }

    WAVE_FENCE();
    #pragma unroll
    for (int j = 0; j < 16; ++j) {
        int i = j * 64 + lane;
        actions[i] = act[i];
    }
}

extern "C" void kernel_launch(void* const* d_in, const int* in_sizes, int n_in,
                              void* d_out, int out_size, void* d_ws, size_t ws_size,
                              hipStream_t stream) {
    (void)in_sizes; (void)n_in; (void)out_size; (void)ws_size;
    const float* scores = (const float*)d_in[0];
    const int* cont = (const int*)d_in[1];
    const int* prev = (const int*)d_in[2];
    float* out = (float*)d_out;
    float* actions = out;
    float* policy = out + MROWS;

    char* ws = (char*)d_ws;
    float* pmax = (float*)(ws + 0);            // 256 f
    float* psum = (float*)(ws + 1024);         // 256 f
    unsigned* bitmap = (unsigned*)(ws + 2304); // 128 u32
    u64* keys16 = (u64*)(ws + 4096);           // 16384 u64 (sorted in place)

    k_partial_max<<<256, 256, 0, stream>>>(scores, pmax);
    k_partial_sum2<<<256, 256, 0, stream>>>(scores, pmax, psum, bitmap, cont, prev);
    k_policy_top16<<<MROWS, 256, 0, stream>>>(scores, pmax, psum, bitmap, cont,
                                              policy, keys16);

    void* args[] = {(void*)&keys16, (void*)&cont, (void*)&prev,
                    (void*)&actions, (void*)&bitmap, (void*)&policy};
    hipLaunchCooperativeKernel(reinterpret_cast<void*>(k_sortscan),
                               dim3(SBLOCKS), dim3(1024), args, 0, stream);
}

// Round 5
// 174.521 us; speedup vs baseline: 1.4642x; 1.4642x over previous
//
#include <hip/hip_runtime.h>
#include <cstdint>
#include <cstddef>

#define MROWS 1024
#define NCOLS 4096
#define TOPK 8
#define NKEYS (MROWS * TOPK)   // 8192

typedef unsigned long long u64;

// key = (p_bits << 22) | ((1023-row) << 12) | (4095-col)
// u64 descending == p desc, then row asc, then col asc (flat-index tie-break).
__device__ inline int key_col(u64 k) { return (NCOLS - 1) - (int)(k & 0xFFFull); }
__device__ inline int key_row(u64 k) { return (MROWS - 1) - (int)((k >> 12) & 0x3FFull); }

// single-wave LDS ordering fence: wait LDS only, do NOT drain vmcnt
#define WAVE_FENCE() __asm__ volatile("s_waitcnt lgkmcnt(0)" ::: "memory")

__device__ inline float wave_max_f(float v) {
    #pragma unroll
    for (int off = 32; off >= 1; off >>= 1)
        v = fmaxf(v, __shfl_xor(v, off, 64));
    return v;
}
__device__ inline float wave_sum_f(float v) {
    #pragma unroll
    for (int off = 32; off >= 1; off >>= 1)
        v += __shfl_xor(v, off, 64);
    return v;
}
__device__ inline u64 wave_max_u64(u64 v) {
    #pragma unroll
    for (int off = 32; off >= 1; off >>= 1) {
        u64 o = __shfl_xor(v, off, 64);
        v = o > v ? o : v;
    }
    return v;
}

// ---------------- K1: online softmax partials (bmax,bsum) + bitmap -------------
__global__ __launch_bounds__(256) void k_stats(const float* __restrict__ s,
                                               float* __restrict__ bmax,
                                               float* __restrict__ bsum,
                                               unsigned* __restrict__ bitmap,
                                               const int* __restrict__ cont,
                                               const int* __restrict__ prev) {
    int b = blockIdx.x, t = threadIdx.x;
    __shared__ float fred[4];
    if (b == 0 && t < 128) bitmap[t] = 0u;
    const float4* s4 = (const float4*)s;
    int base = b * 4096 + t;
    float4 vv[16];
    #pragma unroll
    for (int i = 0; i < 16; ++i) vv[i] = s4[base + i * 256];
    float m = -3.4e38f;
    #pragma unroll
    for (int i = 0; i < 16; ++i)
        m = fmaxf(m, fmaxf(fmaxf(vv[i].x, vv[i].y), fmaxf(vv[i].z, vv[i].w)));
    m = wave_max_f(m);
    if ((t & 63) == 0) fred[t >> 6] = m;
    __syncthreads();
    float lmax = fmaxf(fmaxf(fred[0], fred[1]), fmaxf(fred[2], fred[3]));
    float acc = 0.0f;
    #pragma unroll
    for (int i = 0; i < 16; ++i)
        acc += expf(vv[i].x - lmax) + expf(vv[i].y - lmax) +
               expf(vv[i].z - lmax) + expf(vv[i].w - lmax);
    acc = wave_sum_f(acc);
    __syncthreads();
    if ((t & 63) == 0) fred[t >> 6] = acc;
    __syncthreads();
    if (t == 0) {
        bmax[b] = lmax;
        bsum[b] = fred[0] + fred[1] + fred[2] + fred[3];
    }
    if (b == 0) {
        for (int i = t; i < MROWS; i += 256) {
            if (cont[i]) {
                int c = prev[i];
                atomicOr(&bitmap[c >> 5], 1u << (c & 31));
            }
        }
    }
}

// ---------------- K2: policy write (float4) + per-row masked top-8 keys --------
__global__ __launch_bounds__(256) void k_policy_top8(const float* __restrict__ s,
                                                     const float* __restrict__ bmax,
                                                     const float* __restrict__ bsum,
                                                     const unsigned* __restrict__ bitmap,
                                                     const int* __restrict__ cont,
                                                     float* __restrict__ policy,
                                                     u64* __restrict__ outkeys) {
    __shared__ u64 keys[NCOLS];   // 32 KiB
    __shared__ u64 red[4];
    __shared__ float fred[4];
    int r = blockIdx.x, t = threadIdx.x;
    // combine block-local (max,sum) partials: gmax, gsum
    float bm = bmax[t];
    float m = wave_max_f(bm);
    if ((t & 63) == 0) fred[t >> 6] = m;
    __syncthreads();
    float gmax = fmaxf(fmaxf(fred[0], fred[1]), fmaxf(fred[2], fred[3]));
    float corr = bsum[t] * expf(bm - gmax);
    corr = wave_sum_f(corr);
    __syncthreads();
    if ((t & 63) == 0) fred[t >> 6] = corr;
    __syncthreads();
    float gsum = fred[0] + fred[1] + fred[2] + fred[3];
    float inv = 1.0f / gsum;

    int cg_ = cont[r];
    const float4* s4 = (const float4*)(s + (size_t)r * NCOLS);
    float4* p4 = (float4*)(policy + (size_t)r * NCOLS);
    u64 rowpart = (u64)(MROWS - 1 - r) << 12;
    #pragma unroll
    for (int i = 0; i < 4; ++i) {
        int f = t + i * 256;
        float4 v = s4[f];
        float4 pv;
        pv.x = expf(v.x - gmax) * inv;
        pv.y = expf(v.y - gmax) * inv;
        pv.z = expf(v.z - gmax) * inv;
        pv.w = expf(v.w - gmax) * inv;
        p4[f] = pv;
        int c0 = 4 * f;
        unsigned bmw = bitmap[c0 >> 5];
        float pe[4] = {pv.x, pv.y, pv.z, pv.w};
        #pragma unroll
        for (int e = 0; e < 4; ++e) {
            int c = c0 + e;
            u64 kk = 0ull;
            if (!cg_ && !((bmw >> (c & 31)) & 1u))
                kk = ((u64)__float_as_uint(pe[e]) << 22) | rowpart | (u64)(NCOLS - 1 - c);
            keys[c] = kk;
        }
    }
    __syncthreads();
    if (cg_) {
        if (t < TOPK) outkeys[r * TOPK + t] = 0ull;
        return;
    }
    for (int pass = 0; pass < TOPK; ++pass) {
        u64 best = 0ull;
        #pragma unroll
        for (int i = 0; i < 16; ++i) {
            u64 kk = keys[t + i * 256];
            best = kk > best ? kk : best;
        }
        best = wave_max_u64(best);
        if ((t & 63) == 0) red[t >> 6] = best;
        __syncthreads();
        if (t == 0) {
            u64 b0 = red[0] > red[1] ? red[0] : red[1];
            u64 b1 = red[2] > red[3] ? red[2] : red[3];
            u64 b = b0 > b1 ? b0 : b1;
            outkeys[r * TOPK + pass] = b;
            keys[key_col(b)] = 0ull;
        }
        __syncthreads();
    }
}

// ---------------- S1: local bitonic full sort, 4 blocks x 2048 keys ------------
__global__ __launch_bounds__(1024) void k_sort1(u64* __restrict__ keys) {
    __shared__ u64 sk[2048];   // 16 KiB
    int t = threadIdx.x;
    int off = blockIdx.x * 2048;
    sk[t] = keys[off + t];
    sk[t + 1024] = keys[off + t + 1024];
    __syncthreads();
    for (int k = 2; k <= 2048; k <<= 1) {
        for (int j = k >> 1; j >= 1; j >>= 1) {
            int i = ((t & ~(j - 1)) << 1) | (t & (j - 1));
            int p = i | j;
            bool desc = (((off + i) & k) == 0);
            u64 a = sk[i], bb = sk[p];
            bool sw = desc ? (a < bb) : (a > bb);
            if (sw) { sk[i] = bb; sk[p] = a; }
            __syncthreads();
        }
    }
    keys[off + t] = sk[t];
    keys[off + t + 1024] = sk[t + 1024];
}

// ---------------- S2: k=4096 stage (j=2048..1), 2 blocks x 4096 keys -----------
__global__ __launch_bounds__(1024) void k_sort2(u64* __restrict__ keys) {
    __shared__ u64 sk[4096];   // 32 KiB
    int t = threadIdx.x;
    int off = blockIdx.x * 4096;
    sk[t] = keys[off + t];
    sk[t + 1024] = keys[off + t + 1024];
    sk[t + 2048] = keys[off + t + 2048];
    sk[t + 3072] = keys[off + t + 3072];
    __syncthreads();
    bool desc = ((off & 4096) == 0);   // block 0 desc, block 1 asc
    for (int j = 2048; j >= 1; j >>= 1) {
        #pragma unroll
        for (int q = 0; q < 2; ++q) {
            int idx = t + q * 1024;
            int i = ((idx & ~(j - 1)) << 1) | (idx & (j - 1));
            int p = i | j;
            u64 a = sk[i], bb = sk[p];
            bool sw = desc ? (a < bb) : (a > bb);
            if (sw) { sk[i] = bb; sk[p] = a; }
        }
        __syncthreads();
    }
    keys[off + t] = sk[t];
    keys[off + t + 1024] = sk[t + 1024];
    keys[off + t + 2048] = sk[t + 2048];
    keys[off + t + 3072] = sk[t + 3072];
}

// ---------------- S3: k=8192, j=4096 global CE pass (all desc) -----------------
__global__ __launch_bounds__(256) void k_sort3(u64* __restrict__ keys) {
    int i = blockIdx.x * 256 + threadIdx.x;   // 0..4095
    u64 a = keys[i], b = keys[i + 4096];
    if (a < b) { keys[i] = b; keys[i + 4096] = a; }
}

// ---------------- S4: k=8192, j=2048..1 local finish (all desc), 2 blocks ------
__global__ __launch_bounds__(1024) void k_sort4(u64* __restrict__ keys) {
    __shared__ u64 sk[4096];
    int t = threadIdx.x;
    int off = blockIdx.x * 4096;
    sk[t] = keys[off + t];
    sk[t + 1024] = keys[off + t + 1024];
    sk[t + 2048] = keys[off + t + 2048];
    sk[t + 3072] = keys[off + t + 3072];
    __syncthreads();
    for (int j = 2048; j >= 1; j >>= 1) {
        #pragma unroll
        for (int q = 0; q < 2; ++q) {
            int idx = t + q * 1024;
            int i = ((idx & ~(j - 1)) << 1) | (idx & (j - 1));
            int p = i | j;
            u64 a = sk[i], bb = sk[p];
            if (a < bb) { sk[i] = bb; sk[p] = a; }
        }
        __syncthreads();
    }
    keys[off + t] = sk[t];
    keys[off + t + 1024] = sk[t + 1024];
    keys[off + t + 2048] = sk[t + 2048];
    keys[off + t + 3072] = sk[t + 3072];
}

// ---------------- K5: single-wave scan, ballot-eq leader-round resolve ---------
__global__ __launch_bounds__(64) void k_scan(const int* __restrict__ cont,
                                             const int* __restrict__ prev,
                                             float* __restrict__ actions,
                                             const u64* __restrict__ sorted,
                                             const unsigned* __restrict__ bitmap,
                                             const float* __restrict__ policy) {
    __shared__ unsigned rowdone[MROWS / 32];   // 32
    __shared__ unsigned coldone[NCOLS / 32];   // 128
    __shared__ float act[MROWS];
    int lane = threadIdx.x;
    if (lane < 32) rowdone[lane] = 0u;
    coldone[lane] = bitmap[lane];
    coldone[lane + 64] = bitmap[lane + 64];
    int K = 0;
    #pragma unroll
    for (int j = 0; j < 16; ++j) {
        int i = j * 64 + lane;
        int cgf = cont[i];
        act[i] = cgf ? (float)prev[i] : -1.0f;
        if (cgf) atomicOr(&rowdone[i >> 5], 1u << (i & 31));
        K += (cgf == 0);
    }
    #pragma unroll
    for (int off2 = 32; off2 >= 1; off2 >>= 1) K += __shfl_xor(K, off2, 64);
    WAVE_FENCE();

    int assigned = 0;
    u64 key = sorted[lane];
    u64 kp1 = sorted[64 + lane];
    u64 lower = (1ull << lane) - 1ull;
    for (int base = 0; base < NKEYS && assigned < K; base += 64) {
        u64 kp2 = (base + 128 < NKEYS) ? sorted[base + 128 + lane] : 0ull;
        bool valid = key != 0ull;
        if (__ballot(valid) == 0ull) break;
        int row = key_row(key);
        int col = key_col(key);
        bool rfree = valid && !((rowdone[row >> 5] >> (row & 31)) & 1u);
        bool cfree = valid && !((coldone[col >> 5] >> (col & 31)) & 1u);
        u64 A = __ballot(rfree && cfree);
        u64 commit = 0ull;
        if (A != 0ull) {
            if ((A & (A - 1ull)) == 0ull) {
                commit = A;   // single candidate, no conflict possible
            } else {
                // per-lane equal-row / equal-col masks via bit-ballots
                u64 eq_r = ~0ull, eq_c = ~0ull;
                #pragma unroll
                for (int b = 0; b < 10; ++b) {
                    u64 bal = __ballot((row >> b) & 1);
                    eq_r &= ((row >> b) & 1) ? bal : ~bal;
                }
                #pragma unroll
                for (int b = 0; b < 12; ++b) {
                    u64 bal = __ballot((col >> b) & 1);
                    eq_c &= ((col >> b) & 1) ? bal : ~bal;
                }
                u64 eq = eq_r | eq_c;
                // leader rounds: exact greedy in sorted (lane) order
                while (A) {
                    bool mine = (A >> lane) & 1ull;
                    bool lead = mine && ((eq & A & lower) == 0ull);
                    u64 L = __ballot(lead);
                    commit |= L;
                    bool die = mine && !lead && ((eq & L) != 0ull);
                    u64 D = __ballot(die);
                    A &= ~(L | D);
                }
            }
            if ((commit >> lane) & 1ull) {
                atomicOr(&rowdone[row >> 5], 1u << (row & 31));
                atomicOr(&coldone[col >> 5], 1u << (col & 31));
                act[row] = (float)col;
            }
            assigned += __popcll(commit);
        }
        key = kp1; kp1 = kp2;
        WAVE_FENCE();
    }

    // exact-greedy fallback for rows that exhausted their top-8 (P ~ 0.7%)
    for (int guard = 0; assigned < K && guard < 2048; ++guard) {
        u64 best = 0ull;
        for (int r = 0; r < MROWS; ++r) {
            if ((rowdone[r >> 5] >> (r & 31)) & 1u) continue;
            const float* prow = policy + (size_t)r * NCOLS;
            u64 rowpart = (u64)(MROWS - 1 - r) << 12;
            for (int c = lane; c < NCOLS; c += 64) {
                if ((coldone[c >> 5] >> (c & 31)) & 1u) continue;
                u64 kk = ((u64)__float_as_uint(prow[c]) << 22) | rowpart |
                         (u64)(NCOLS - 1 - c);
                best = kk > best ? kk : best;
            }
        }
        best = wave_max_u64(best);
        if (best == 0ull) break;
        if (lane == 0) {
            int row = key_row(best), col = key_col(best);
            rowdone[row >> 5] |= 1u << (row & 31);
            coldone[col >> 5] |= 1u << (col & 31);
            act[row] = (float)col;
        }
        ++assigned;
        WAVE_FENCE();
    }

    WAVE_FENCE();
    #pragma unroll
    for (int j = 0; j < 16; ++j) {
        int i = j * 64 + lane;
        actions[i] = act[i];
    }
}

extern "C" void kernel_launch(void* const* d_in, const int* in_sizes, int n_in,
                              void* d_out, int out_size, void* d_ws, size_t ws_size,
                              hipStream_t stream) {
    (void)in_sizes; (void)n_in; (void)out_size; (void)ws_size;
    const float* scores = (const float*)d_in[0];
    const int* cont = (const int*)d_in[1];
    const int* prev = (const int*)d_in[2];
    float* out = (float*)d_out;
    float* actions = out;
    float* policy = out + MROWS;

    char* ws = (char*)d_ws;
    float* bmax = (float*)(ws + 0);            // 256 f
    float* bsum = (float*)(ws + 1024);         // 256 f
    unsigned* bitmap = (unsigned*)(ws + 2304); // 128 u32
    u64* keys8 = (u64*)(ws + 4096);            // 8192 u64 (sorted in place)

    k_stats<<<256, 256, 0, stream>>>(scores, bmax, bsum, bitmap, cont, prev);
    k_policy_top8<<<MROWS, 256, 0, stream>>>(scores, bmax, bsum, bitmap, cont,
                                             policy, keys8);
    k_sort1<<<4, 1024, 0, stream>>>(keys8);
    k_sort2<<<2, 1024, 0, stream>>>(keys8);
    k_sort3<<<16, 256, 0, stream>>>(keys8);
    k_sort4<<<2, 1024, 0, stream>>>(keys8);
    k_scan<<<1, 64, 0, stream>>>(cont, prev, actions, keys8, bitmap, policy);
}

// Round 6
// 166.994 us; speedup vs baseline: 1.5302x; 1.0451x over previous
//
#include <hip/hip_runtime.h>
#include <cstdint>
#include <cstddef>

#define MROWS 1024
#define NCOLS 4096
#define TOPK 8
#define NKEYS (MROWS * TOPK)   // 8192

typedef unsigned long long u64;

// key = (p_bits << 22) | ((1023-row) << 12) | (4095-col)
// u64 descending == p desc, then row asc, then col asc (flat-index tie-break).
__device__ inline int key_col(u64 k) { return (NCOLS - 1) - (int)(k & 0xFFFull); }
__device__ inline int key_row(u64 k) { return (MROWS - 1) - (int)((k >> 12) & 0x3FFull); }

// single-wave LDS ordering fence: wait LDS only, do NOT drain vmcnt
#define WAVE_FENCE() __asm__ volatile("s_waitcnt lgkmcnt(0)" ::: "memory")

__device__ inline float wave_max_f(float v) {
    #pragma unroll
    for (int off = 32; off >= 1; off >>= 1)
        v = fmaxf(v, __shfl_xor(v, off, 64));
    return v;
}
__device__ inline float wave_sum_f(float v) {
    #pragma unroll
    for (int off = 32; off >= 1; off >>= 1)
        v += __shfl_xor(v, off, 64);
    return v;
}
__device__ inline u64 wave_max_u64(u64 v) {
    #pragma unroll
    for (int off = 32; off >= 1; off >>= 1) {
        u64 o = __shfl_xor(v, off, 64);
        v = o > v ? o : v;
    }
    return v;
}

// ---------------- K1: online softmax partials (bmax,bsum) + bitmap -------------
__global__ __launch_bounds__(256) void k_stats(const float* __restrict__ s,
                                               float* __restrict__ bmax,
                                               float* __restrict__ bsum,
                                               unsigned* __restrict__ bitmap,
                                               const int* __restrict__ cont,
                                               const int* __restrict__ prev) {
    int b = blockIdx.x, t = threadIdx.x;
    __shared__ float fred[4];
    if (b == 0 && t < 128) bitmap[t] = 0u;
    const float4* s4 = (const float4*)s;
    int base = b * 4096 + t;
    float4 vv[16];
    #pragma unroll
    for (int i = 0; i < 16; ++i) vv[i] = s4[base + i * 256];
    float m = -3.4e38f;
    #pragma unroll
    for (int i = 0; i < 16; ++i)
        m = fmaxf(m, fmaxf(fmaxf(vv[i].x, vv[i].y), fmaxf(vv[i].z, vv[i].w)));
    m = wave_max_f(m);
    if ((t & 63) == 0) fred[t >> 6] = m;
    __syncthreads();
    float lmax = fmaxf(fmaxf(fred[0], fred[1]), fmaxf(fred[2], fred[3]));
    float acc = 0.0f;
    #pragma unroll
    for (int i = 0; i < 16; ++i)
        acc += expf(vv[i].x - lmax) + expf(vv[i].y - lmax) +
               expf(vv[i].z - lmax) + expf(vv[i].w - lmax);
    acc = wave_sum_f(acc);
    __syncthreads();
    if ((t & 63) == 0) fred[t >> 6] = acc;
    __syncthreads();
    if (t == 0) {
        bmax[b] = lmax;
        bsum[b] = fred[0] + fred[1] + fred[2] + fred[3];
    }
    if (b == 0) {
        for (int i = t; i < MROWS; i += 256) {
            if (cont[i]) {
                int c = prev[i];
                atomicOr(&bitmap[c >> 5], 1u << (c & 31));
            }
        }
    }
}

// ---------------- K2: policy write (float4) + per-row masked top-8 keys --------
__global__ __launch_bounds__(256) void k_policy_top8(const float* __restrict__ s,
                                                     const float* __restrict__ bmax,
                                                     const float* __restrict__ bsum,
                                                     const unsigned* __restrict__ bitmap,
                                                     const int* __restrict__ cont,
                                                     float* __restrict__ policy,
                                                     u64* __restrict__ outkeys) {
    __shared__ u64 keys[NCOLS];   // 32 KiB
    __shared__ u64 red[4];
    __shared__ float fred[4];
    int r = blockIdx.x, t = threadIdx.x;
    float bm = bmax[t];
    float m = wave_max_f(bm);
    if ((t & 63) == 0) fred[t >> 6] = m;
    __syncthreads();
    float gmax = fmaxf(fmaxf(fred[0], fred[1]), fmaxf(fred[2], fred[3]));
    float corr = bsum[t] * expf(bm - gmax);
    corr = wave_sum_f(corr);
    __syncthreads();
    if ((t & 63) == 0) fred[t >> 6] = corr;
    __syncthreads();
    float gsum = fred[0] + fred[1] + fred[2] + fred[3];
    float inv = 1.0f / gsum;

    int cg_ = cont[r];
    const float4* s4 = (const float4*)(s + (size_t)r * NCOLS);
    float4* p4 = (float4*)(policy + (size_t)r * NCOLS);
    u64 rowpart = (u64)(MROWS - 1 - r) << 12;
    #pragma unroll
    for (int i = 0; i < 4; ++i) {
        int f = t + i * 256;
        float4 v = s4[f];
        float4 pv;
        pv.x = expf(v.x - gmax) * inv;
        pv.y = expf(v.y - gmax) * inv;
        pv.z = expf(v.z - gmax) * inv;
        pv.w = expf(v.w - gmax) * inv;
        p4[f] = pv;
        int c0 = 4 * f;
        unsigned bmw = bitmap[c0 >> 5];
        float pe[4] = {pv.x, pv.y, pv.z, pv.w};
        #pragma unroll
        for (int e = 0; e < 4; ++e) {
            int c = c0 + e;
            u64 kk = 0ull;
            if (!cg_ && !((bmw >> (c & 31)) & 1u))
                kk = ((u64)__float_as_uint(pe[e]) << 22) | rowpart | (u64)(NCOLS - 1 - c);
            keys[c] = kk;
        }
    }
    __syncthreads();
    if (cg_) {
        if (t < TOPK) outkeys[r * TOPK + t] = 0ull;
        return;
    }
    for (int pass = 0; pass < TOPK; ++pass) {
        u64 best = 0ull;
        #pragma unroll
        for (int i = 0; i < 16; ++i) {
            u64 kk = keys[t + i * 256];
            best = kk > best ? kk : best;
        }
        best = wave_max_u64(best);
        if ((t & 63) == 0) red[t >> 6] = best;
        __syncthreads();
        if (t == 0) {
            u64 b0 = red[0] > red[1] ? red[0] : red[1];
            u64 b1 = red[2] > red[3] ? red[2] : red[3];
            u64 b = b0 > b1 ? b0 : b1;
            outkeys[r * TOPK + pass] = b;
            keys[key_col(b)] = 0ull;
        }
        __syncthreads();
    }
}

// ---------------- S1: local bitonic full sort, 4 blocks x 2048 keys ------------
// leaves chunk sorted desc iff (chunk_base & 2048)==0 (alternating, bitonic-ready)
__global__ __launch_bounds__(1024) void k_sort1(u64* __restrict__ keys) {
    __shared__ u64 sk[2048];   // 16 KiB
    int t = threadIdx.x;
    int off = blockIdx.x * 2048;
    sk[t] = keys[off + t];
    sk[t + 1024] = keys[off + t + 1024];
    __syncthreads();
    for (int k = 2; k <= 2048; k <<= 1) {
        for (int j = k >> 1; j >= 1; j >>= 1) {
            int i = ((t & ~(j - 1)) << 1) | (t & (j - 1));
            int p = i | j;
            bool desc = (((off + i) & k) == 0);
            u64 a = sk[i], bb = sk[p];
            bool sw = desc ? (a < bb) : (a > bb);
            if (sw) { sk[i] = bb; sk[p] = a; }
            __syncthreads();
        }
    }
    keys[off + t] = sk[t];
    keys[off + t + 1024] = sk[t + 1024];
}

// ---------------- K4: single-block k=4096+8192 merge + chunk-filter scan -------
__global__ __launch_bounds__(512) void k_sortscan(const u64* __restrict__ keys_g,
                                                  const int* __restrict__ cont,
                                                  const int* __restrict__ prev,
                                                  float* __restrict__ actions,
                                                  const unsigned* __restrict__ bitmap,
                                                  const float* __restrict__ policy) {
    __shared__ u64 sk[NKEYS];                  // 64 KiB
    __shared__ unsigned rowdone[MROWS / 32];   // 32
    __shared__ unsigned coldone[NCOLS / 32];   // 128
    __shared__ float act[MROWS];               // 4 KiB
    __shared__ unsigned dbuf[256];             // dense candidate list (order-preserving)
    int t = threadIdx.x;

    for (int i = t; i < NKEYS; i += 512) sk[i] = keys_g[i];
    __syncthreads();
    // bitonic levels k=4096 (dirs alternate) and k=8192 (all desc)
    for (int k = 4096; k <= 8192; k <<= 1) {
        for (int j = k >> 1; j >= 1; j >>= 1) {
            #pragma unroll
            for (int q = 0; q < 8; ++q) {
                int idx = t + q * 512;         // 0..4095
                int i = ((idx & ~(j - 1)) << 1) | (idx & (j - 1));
                int p = i | j;
                bool desc = ((i & k) == 0);
                u64 a = sk[i], bb = sk[p];
                bool sw = desc ? (a < bb) : (a > bb);
                if (sw) { sk[i] = bb; sk[p] = a; }
            }
            __syncthreads();
        }
    }

    if (t >= 64) return;   // scan: wave 0 only (no __syncthreads below)
    int lane = t;
    if (lane < 32) rowdone[lane] = 0u;
    coldone[lane] = bitmap[lane];
    coldone[lane + 64] = bitmap[lane + 64];
    int K = 0;
    #pragma unroll
    for (int j = 0; j < 16; ++j) {
        int i = j * 64 + lane;
        int cgf = cont[i];
        act[i] = cgf ? (float)prev[i] : -1.0f;
        if (cgf) atomicOr(&rowdone[i >> 5], 1u << (i & 31));
        K += (cgf == 0);
    }
    #pragma unroll
    for (int off2 = 32; off2 >= 1; off2 >>= 1) K += __shfl_xor(K, off2, 64);
    WAVE_FENCE();

    int assigned = 0;
    u64 lower = (1ull << lane) - 1ull;
    for (int base = 0; base < NKEYS && assigned < K; base += 256) {
        // ---- filter 256 keys -> dense ordered candidate list ----
        int cnt = 0;
        u64 anyvalid = 0ull;
        #pragma unroll
        for (int w = 0; w < 4; ++w) {
            u64 key = sk[base + w * 64 + lane];
            bool valid = key != 0ull;
            anyvalid |= __ballot(valid);
            int row = key_row(key);
            int col = key_col(key);
            bool alive = valid &&
                         !((rowdone[row >> 5] >> (row & 31)) & 1u) &&
                         !((coldone[col >> 5] >> (col & 31)) & 1u);
            u64 bal = __ballot(alive);
            if (alive) {
                int rank = __popcll(bal & lower);
                dbuf[cnt + rank] = (unsigned)((row << 12) | col);
            }
            cnt += __popcll(bal);
        }
        if (anyvalid == 0ull) break;   // sorted-desc: rest is zero padding
        WAVE_FENCE();                  // dbuf writes visible before reads

        // ---- resolve dense list in 64-wide windows (exact greedy order) ----
        for (int s0 = 0; s0 < cnt && assigned < K; s0 += 64) {
            int widx = s0 + lane;
            bool have = widx < cnt;
            unsigned rc = have ? dbuf[widx] : 0u;
            int row = rc >> 12, col = rc & 4095;
            bool rfree = have && !((rowdone[row >> 5] >> (row & 31)) & 1u);
            bool cfree = have && !((coldone[col >> 5] >> (col & 31)) & 1u);
            u64 A = __ballot(rfree && cfree);
            if (A != 0ull) {
                u64 commit = 0ull;
                if ((A & (A - 1ull)) == 0ull) {
                    commit = A;
                } else {
                    // per-lane equal-row/equal-col masks via 22 bit-ballots on rc
                    u64 eq_r = ~0ull, eq_c = ~0ull;
                    #pragma unroll
                    for (int b = 12; b < 22; ++b) {
                        u64 bal = __ballot((rc >> b) & 1u);
                        eq_r &= ((rc >> b) & 1u) ? bal : ~bal;
                    }
                    #pragma unroll
                    for (int b = 0; b < 12; ++b) {
                        u64 bal = __ballot((rc >> b) & 1u);
                        eq_c &= ((rc >> b) & 1u) ? bal : ~bal;
                    }
                    u64 eq = eq_r | eq_c;
                    while (A) {   // leader rounds: exact greedy in sorted order
                        bool mine = (A >> lane) & 1ull;
                        bool lead = mine && ((eq & A & lower) == 0ull);
                        u64 L = __ballot(lead);
                        commit |= L;
                        bool die = mine && !lead && ((eq & L) != 0ull);
                        u64 D = __ballot(die);
                        A &= ~(L | D);
                    }
                }
                if ((commit >> lane) & 1ull) {
                    atomicOr(&rowdone[row >> 5], 1u << (row & 31));
                    atomicOr(&coldone[col >> 5], 1u << (col & 31));
                    act[row] = (float)col;
                }
                assigned += __popcll(commit);
                WAVE_FENCE();   // commits visible before next window's checks
            }
        }
        WAVE_FENCE();           // commits visible before next chunk's filter
    }

    // exact-greedy fallback for rows that exhausted their top-8 (P ~ 1e-7)
    for (int guard = 0; assigned < K && guard < 2048; ++guard) {
        u64 best = 0ull;
        for (int r = 0; r < MROWS; ++r) {
            if ((rowdone[r >> 5] >> (r & 31)) & 1u) continue;
            const float* prow = policy + (size_t)r * NCOLS;
            u64 rowpart = (u64)(MROWS - 1 - r) << 12;
            for (int c = lane; c < NCOLS; c += 64) {
                if ((coldone[c >> 5] >> (c & 31)) & 1u) continue;
                u64 kk = ((u64)__float_as_uint(prow[c]) << 22) | rowpart |
                         (u64)(NCOLS - 1 - c);
                best = kk > best ? kk : best;
            }
        }
        best = wave_max_u64(best);
        if (best == 0ull) break;
        if (lane == 0) {
            int row = key_row(best), col = key_col(best);
            rowdone[row >> 5] |= 1u << (row & 31);
            coldone[col >> 5] |= 1u << (col & 31);
            act[row] = (float)col;
        }
        ++assigned;
        WAVE_FENCE();
    }

    WAVE_FENCE();
    #pragma unroll
    for (int j = 0; j < 16; ++j) {
        int i = j * 64 + lane;
        actions[i] = act[i];
    }
}

extern "C" void kernel_launch(void* const* d_in, const int* in_sizes, int n_in,
                              void* d_out, int out_size, void* d_ws, size_t ws_size,
                              hipStream_t stream) {
    (void)in_sizes; (void)n_in; (void)out_size; (void)ws_size;
    const float* scores = (const float*)d_in[0];
    const int* cont = (const int*)d_in[1];
    const int* prev = (const int*)d_in[2];
    float* out = (float*)d_out;
    float* actions = out;
    float* policy = out + MROWS;

    char* ws = (char*)d_ws;
    float* bmax = (float*)(ws + 0);            // 256 f
    float* bsum = (float*)(ws + 1024);         // 256 f
    unsigned* bitmap = (unsigned*)(ws + 2304); // 128 u32
    u64* keys8 = (u64*)(ws + 4096);            // 8192 u64 (sorted in place)

    k_stats<<<256, 256, 0, stream>>>(scores, bmax, bsum, bitmap, cont, prev);
    k_policy_top8<<<MROWS, 256, 0, stream>>>(scores, bmax, bsum, bitmap, cont,
                                             policy, keys8);
    k_sort1<<<4, 1024, 0, stream>>>(keys8);
    k_sortscan<<<1, 512, 0, stream>>>(keys8, cont, prev, actions, bitmap, policy);
}

// Round 7
// 102.049 us; speedup vs baseline: 2.5041x; 1.6364x over previous
//
#include <hip/hip_runtime.h>
#include <cstdint>
#include <cstddef>

#define MROWS 1024
#define NCOLS 4096
#define TOPK 8
#define NKEYS (MROWS * TOPK)   // 8192

typedef unsigned long long u64;

// key = (p_bits << 22) | ((1023-row) << 12) | (4095-col)
// u64 descending == p desc, then row asc, then col asc (flat-index tie-break).
__device__ inline int key_col(u64 k) { return (NCOLS - 1) - (int)(k & 0xFFFull); }
__device__ inline int key_row(u64 k) { return (MROWS - 1) - (int)((k >> 12) & 0x3FFull); }

// single-wave LDS ordering fence: wait LDS only, do NOT drain vmcnt
#define WAVE_FENCE() __asm__ volatile("s_waitcnt lgkmcnt(0)" ::: "memory")

__device__ inline float wave_max_f(float v) {
    #pragma unroll
    for (int off = 32; off >= 1; off >>= 1)
        v = fmaxf(v, __shfl_xor(v, off, 64));
    return v;
}
__device__ inline float wave_sum_f(float v) {
    #pragma unroll
    for (int off = 32; off >= 1; off >>= 1)
        v += __shfl_xor(v, off, 64);
    return v;
}
__device__ inline u64 wave_max_u64(u64 v) {
    #pragma unroll
    for (int off = 32; off >= 1; off >>= 1) {
        u64 o = __shfl_xor(v, off, 64);
        v = o > v ? o : v;
    }
    return v;
}

// ---------------- K1: online softmax partials (bmax,bsum) + bitmap -------------
__global__ __launch_bounds__(256) void k_stats(const float* __restrict__ s,
                                               float* __restrict__ bmax,
                                               float* __restrict__ bsum,
                                               unsigned* __restrict__ bitmap,
                                               const int* __restrict__ cont,
                                               const int* __restrict__ prev) {
    int b = blockIdx.x, t = threadIdx.x;
    __shared__ float fred[4];
    if (b == 0 && t < 128) bitmap[t] = 0u;
    const float4* s4 = (const float4*)s;
    int base = b * 4096 + t;
    float4 vv[16];
    #pragma unroll
    for (int i = 0; i < 16; ++i) vv[i] = s4[base + i * 256];
    float m = -3.4e38f;
    #pragma unroll
    for (int i = 0; i < 16; ++i)
        m = fmaxf(m, fmaxf(fmaxf(vv[i].x, vv[i].y), fmaxf(vv[i].z, vv[i].w)));
    m = wave_max_f(m);
    if ((t & 63) == 0) fred[t >> 6] = m;
    __syncthreads();
    float lmax = fmaxf(fmaxf(fred[0], fred[1]), fmaxf(fred[2], fred[3]));
    float acc = 0.0f;
    #pragma unroll
    for (int i = 0; i < 16; ++i)
        acc += expf(vv[i].x - lmax) + expf(vv[i].y - lmax) +
               expf(vv[i].z - lmax) + expf(vv[i].w - lmax);
    acc = wave_sum_f(acc);
    __syncthreads();
    if ((t & 63) == 0) fred[t >> 6] = acc;
    __syncthreads();
    if (t == 0) {
        bmax[b] = lmax;
        bsum[b] = fred[0] + fred[1] + fred[2] + fred[3];
    }
    if (b == 0) {
        for (int i = t; i < MROWS; i += 256) {
            if (cont[i]) {
                int c = prev[i];
                atomicOr(&bitmap[c >> 5], 1u << (c & 31));
            }
        }
    }
}

// ---------------- K2: policy write (float4) + per-row masked top-8 keys --------
__global__ __launch_bounds__(256) void k_policy_top8(const float* __restrict__ s,
                                                     const float* __restrict__ bmax,
                                                     const float* __restrict__ bsum,
                                                     const unsigned* __restrict__ bitmap,
                                                     const int* __restrict__ cont,
                                                     float* __restrict__ policy,
                                                     u64* __restrict__ outkeys) {
    __shared__ u64 keys[NCOLS];   // 32 KiB
    __shared__ u64 red[4];
    __shared__ float fred[4];
    int r = blockIdx.x, t = threadIdx.x;
    float bm = bmax[t];
    float m = wave_max_f(bm);
    if ((t & 63) == 0) fred[t >> 6] = m;
    __syncthreads();
    float gmax = fmaxf(fmaxf(fred[0], fred[1]), fmaxf(fred[2], fred[3]));
    float corr = bsum[t] * expf(bm - gmax);
    corr = wave_sum_f(corr);
    __syncthreads();
    if ((t & 63) == 0) fred[t >> 6] = corr;
    __syncthreads();
    float gsum = fred[0] + fred[1] + fred[2] + fred[3];
    float inv = 1.0f / gsum;

    int cg_ = cont[r];
    const float4* s4 = (const float4*)(s + (size_t)r * NCOLS);
    float4* p4 = (float4*)(policy + (size_t)r * NCOLS);
    u64 rowpart = (u64)(MROWS - 1 - r) << 12;
    #pragma unroll
    for (int i = 0; i < 4; ++i) {
        int f = t + i * 256;
        float4 v = s4[f];
        float4 pv;
        pv.x = expf(v.x - gmax) * inv;
        pv.y = expf(v.y - gmax) * inv;
        pv.z = expf(v.z - gmax) * inv;
        pv.w = expf(v.w - gmax) * inv;
        p4[f] = pv;
        int c0 = 4 * f;
        unsigned bmw = bitmap[c0 >> 5];
        float pe[4] = {pv.x, pv.y, pv.z, pv.w};
        #pragma unroll
        for (int e = 0; e < 4; ++e) {
            int c = c0 + e;
            u64 kk = 0ull;
            if (!cg_ && !((bmw >> (c & 31)) & 1u))
                kk = ((u64)__float_as_uint(pe[e]) << 22) | rowpart | (u64)(NCOLS - 1 - c);
            keys[c] = kk;
        }
    }
    __syncthreads();
    if (cg_) {
        if (t < TOPK) outkeys[r * TOPK + t] = 0ull;
        return;
    }
    for (int pass = 0; pass < TOPK; ++pass) {
        u64 best = 0ull;
        #pragma unroll
        for (int i = 0; i < 16; ++i) {
            u64 kk = keys[t + i * 256];
            best = kk > best ? kk : best;
        }
        best = wave_max_u64(best);
        if ((t & 63) == 0) red[t >> 6] = best;
        __syncthreads();
        if (t == 0) {
            u64 b0 = red[0] > red[1] ? red[0] : red[1];
            u64 b1 = red[2] > red[3] ? red[2] : red[3];
            u64 b = b0 > b1 ? b0 : b1;
            outkeys[r * TOPK + pass] = b;
            keys[key_col(b)] = 0ull;
        }
        __syncthreads();
    }
}

// ---------------- K3: parallel dominant-edge matching (exact greedy) -----------
// Greedy-by-descending-key == iterate: commit every key that is simultaneously
// its row's best surviving and its column's best surviving (distinct weights).
__global__ __launch_bounds__(1024) void k_match(const u64* __restrict__ keys_g,
                                                const int* __restrict__ cont,
                                                const int* __restrict__ prev,
                                                float* __restrict__ actions,
                                                const unsigned* __restrict__ bitmap,
                                                const float* __restrict__ policy) {
    __shared__ u64 colbest[NCOLS];             // 32 KiB
    __shared__ unsigned coldone[NCOLS / 32];   // 128 u32
    __shared__ unsigned rowdone[MROWS / 32];   // 32 u32 (for fallback bookkeeping)
    __shared__ float act[MROWS];               // 4 KiB
    __shared__ int exh_flag;

    int t = threadIdx.x;   // my row
    #pragma unroll
    for (int i = 0; i < 4; ++i) colbest[t + i * 1024] = 0ull;
    if (t < 128) coldone[t] = bitmap[t];
    if (t < 32) rowdone[t] = 0u;
    if (t == 0) exh_flag = 0;

    int cg_ = cont[t];
    act[t] = cg_ ? (float)prev[t] : -1.0f;
    if (cg_) atomicOr(&rowdone[t >> 5], 1u << (t & 31));
    bool active = (cg_ == 0);

    u64 myk[TOPK];
    {
        const u64* gk = keys_g + (size_t)t * TOPK;
        #pragma unroll
        for (int k = 0; k < TOPK; ++k) myk[k] = gk[k];
    }
    __syncthreads();

    int ki = 0;
    int any = 1;
    for (int round = 0; round < 700; ++round) {
        // ---- Phase A: advance past dead keys; submit all surviving keys ----
        bool subm = false;
        u64 mybest = 0ull;
        int mycol = 0;
        if (active) {
            while (ki < TOPK) {
                int c = key_col(myk[ki]);
                if (myk[ki] == 0ull ||
                    ((coldone[c >> 5] >> (c & 31)) & 1u)) { myk[ki] = 0ull; ++ki; }
                else break;
            }
            if (ki == TOPK) {
                active = false;
                exh_flag = 1;   // row needs exact fallback
            } else {
                subm = true;
                mybest = myk[ki];
                mycol = key_col(mybest);
                #pragma unroll
                for (int k = 0; k < TOPK; ++k) {
                    u64 kk = myk[k];
                    if (k < ki || kk == 0ull) continue;
                    int c = key_col(kk);
                    if ((coldone[c >> 5] >> (c & 31)) & 1u) { myk[k] = 0ull; continue; }
                    atomicMax(&colbest[c], kk);
                }
            }
        }
        any = __syncthreads_count(active ? 1 : 0);
        if (any == 0) break;
        // ---- Phase B: commit dominant edges ----
        if (active && colbest[mycol] == mybest) {
            act[t] = (float)mycol;
            atomicOr(&coldone[mycol >> 5], 1u << (mycol & 31));
            atomicOr(&rowdone[t >> 5], 1u << (t & 31));
            active = false;
        }
        __syncthreads();
        // ---- Phase C: clear this round's submissions ----
        if (subm) {
            #pragma unroll
            for (int k = 0; k < TOPK; ++k) {
                u64 kk = myk[k];
                if (k < ki || kk == 0ull) continue;
                colbest[key_col(kk)] = 0ull;
            }
        }
        __syncthreads();
    }
    __syncthreads();

    // ---- exact-greedy fallback (P ~ 1e-7): wave 0, rows with rowdone bit 0 ----
    if ((exh_flag || any) && t < 64) {
        int lane = t;
        for (int guard = 0; guard < 1200; ++guard) {
            u64 best = 0ull;
            for (int r = 0; r < MROWS; ++r) {
                if ((rowdone[r >> 5] >> (r & 31)) & 1u) continue;
                const float* prow = policy + (size_t)r * NCOLS;
                u64 rowpart = (u64)(MROWS - 1 - r) << 12;
                for (int c = lane; c < NCOLS; c += 64) {
                    if ((coldone[c >> 5] >> (c & 31)) & 1u) continue;
                    u64 kk = ((u64)__float_as_uint(prow[c]) << 22) | rowpart |
                             (u64)(NCOLS - 1 - c);
                    best = kk > best ? kk : best;
                }
            }
            best = wave_max_u64(best);
            if (best == 0ull) break;
            if (lane == 0) {
                int row = key_row(best), col = key_col(best);
                rowdone[row >> 5] |= 1u << (row & 31);
                coldone[col >> 5] |= 1u << (col & 31);
                act[row] = (float)col;
            }
            WAVE_FENCE();
        }
    }
    __syncthreads();
    actions[t] = act[t];
}

extern "C" void kernel_launch(void* const* d_in, const int* in_sizes, int n_in,
                              void* d_out, int out_size, void* d_ws, size_t ws_size,
                              hipStream_t stream) {
    (void)in_sizes; (void)n_in; (void)out_size; (void)ws_size;
    const float* scores = (const float*)d_in[0];
    const int* cont = (const int*)d_in[1];
    const int* prev = (const int*)d_in[2];
    float* out = (float*)d_out;
    float* actions = out;
    float* policy = out + MROWS;

    char* ws = (char*)d_ws;
    float* bmax = (float*)(ws + 0);            // 256 f
    float* bsum = (float*)(ws + 1024);         // 256 f
    unsigned* bitmap = (unsigned*)(ws + 2304); // 128 u32
    u64* keys8 = (u64*)(ws + 4096);            // 8192 u64

    k_stats<<<256, 256, 0, stream>>>(scores, bmax, bsum, bitmap, cont, prev);
    k_policy_top8<<<MROWS, 256, 0, stream>>>(scores, bmax, bsum, bitmap, cont,
                                             policy, keys8);
    k_match<<<1, 1024, 0, stream>>>(keys8, cont, prev, actions, bitmap, policy);
}